// Round 8
// baseline (118.961 us; speedup 1.0000x reference)
//
#include <hip/hip_runtime.h>

#define TLEN 512
#define LOG2E 1.44269504088896340736f

#if __has_builtin(__builtin_amdgcn_exp2f)
#define EXP2F(x) __builtin_amdgcn_exp2f(x)
#else
#define EXP2F(x) __exp2f(x)
#endif
#if __has_builtin(__builtin_amdgcn_rcpf)
#define RCPF(x) __builtin_amdgcn_rcpf(x)
#else
#define RCPF(x) (1.0f / (x))
#endif

// ds_swizzle BitMode xor (epilogue MLP head only, off the hot loop)
#define SWZ(v, xm) __int_as_float(__builtin_amdgcn_ds_swizzle(__float_as_int(v), (((xm) << 10) | 0x1F)))
// Generic DPP: dst = src[permuted lane], all lanes valid
#define DPPF(v, ctrl) __int_as_float(__builtin_amdgcn_update_dpp(__float_as_int(v), __float_as_int(v), (ctrl), 0xF, 0xF, false))
// quad_perm broadcast of quad-lane k
#define QB(v, k) DPPF(v, 0x55 * (k))
// Direction-free lane exchanges within a row of 16 (verified R1/R2/R6/R7, absmax 0):
#define XOR3(v)  DPPF(v, 0x1B)   // quad_perm [3,2,1,0]
#define XOR7(v)  DPPF(v, 0x141)  // ROW_HALF_MIRROR
#define XOR8(v)  DPPF(v, 0x128)  // ROW_ROR:8

struct X4 { float4 a, b, c, d; };   // one timestep: 16 floats, 64 B

// Two-phase design: the serial LSTM chain never touches global memory.
// Phase A (bulk, per 32-step chunk): every lane computes its own gate's
// x-projection for 32 timesteps -- massively parallel loads+FMAs, latency
// self-hiding. Results land in wave-private LDS (t-contiguous, padded rows).
// Phase B (recurrence): 1 ds_read_b128 per 4 steps, prefetched one group
// ahead (~400 cy of chain covers ~120 cy LDS latency). No barriers anywhere.
__global__ __launch_bounds__(256)
__attribute__((amdgpu_waves_per_eu(1, 1)))
void lstm_mlp_kernel(
    const float* __restrict__ x,   // [B,512,16]
    const float* __restrict__ Wk,  // [16,16]
    const float* __restrict__ Wr,  // [4,16]
    const float* __restrict__ bg,  // [16]
    const float* __restrict__ W1,  // [4,64]
    const float* __restrict__ b1,  // [64]
    const float* __restrict__ W2,  // [64,5]
    const float* __restrict__ b2,  // [5]
    float* __restrict__ out,       // [B,5]
    int B)
{
    // xg[wave][row=sl*16+gate][t within chunk], row padded to 36 floats:
    // bank(lane) = (row*36 + t) % 32 -> (4*row + t) % 32 spreads 64 lanes
    // across all 32 banks at the 8-access/bank minimum (full LDS BW).
    // 4 * 64 * 36 * 4B = 36864 B per block. Wave-private -> no barriers.
    __shared__ float xg[4][64][36];

    const int tidx = threadIdx.x;
    const int w    = tidx >> 6;        // wave in block
    const int sl   = (tidx >> 4) & 3;  // seq within wave
    const int i16  = tidx & 15;
    const int j    = i16 >> 2;         // hidden unit owned by this quad
    const int q    = i16 & 3;          // gate type: 0=i, 1=f, 2=g(tanh), 3=o
    const int gate = q * 4 + j;        // column in gates[16] (Keras i,f,g,o)
    const int row  = sl * 16 + i16;    // this lane's private xg row

    const int seq = blockIdx.x * 16 + w * 4 + sl;

    // activation pre-scale folded into weights (verified R2/R6/R7, absmax 0)
    const bool is_g = (q == 2);
    const float k1 = is_g ? (-2.0f * LOG2E) : (-LOG2E);
    const float m1c = is_g ? (-4.0f * LOG2E) : 1.0f;
    const float m0c = is_g ? (2.0f * LOG2E) : 0.0f;

    float wk[16];
#pragma unroll
    for (int f = 0; f < 16; ++f) wk[f] = k1 * Wk[f * 16 + gate];
    const float wr0 = k1 * Wr[(j ^ 0) * 16 + gate];
    const float wr1 = k1 * Wr[(j ^ 1) * 16 + gate];
    const float wr2 = k1 * Wr[(j ^ 2) * 16 + gate];
    const float wr3 = k1 * Wr[(j ^ 3) * 16 + gate];
    const float biasS = k1 * bg[gate];

    const X4* xt = reinterpret_cast<const X4*>(x) + (size_t)seq * TLEN;

    float cs = 0.0f, h = 0.0f;   // cs = -2*log2e * c

#define DOT4S(v, w0_, w1_, w2_, w3_, seed) \
    fmaf((v).x, (w0_), fmaf((v).y, (w1_), fmaf((v).z, (w2_), fmaf((v).w, (w3_), (seed)))))
#define DOTB(Bk) \
    ((DOT4S((Bk).a, wk[0], wk[1], wk[2], wk[3], biasS) + \
      DOT4S((Bk).b, wk[4], wk[5], wk[6], wk[7], 0.0f)) + \
     (DOT4S((Bk).c, wk[8], wk[9], wk[10], wk[11], 0.0f) + \
      DOT4S((Bk).d, wk[12], wk[13], wk[14], wk[15], 0.0f)))

// tree-shaped preactivation sum (depth 3 vs 4), then the LSTM cell update
#define STEP(XD) { \
    float h1_ = XOR7(XOR3(h));   /* h[j^1] */ \
    float h2_ = XOR8(h);         /* h[j^2] */ \
    float h3_ = XOR8(h1_);       /* h[j^3] */ \
    float preA = fmaf(h, wr0, fmaf(h1_, wr1, (XD))); \
    float preB = fmaf(h2_, wr2, h3_ * wr3); \
    float pre = preA + preB; \
    float r_ = RCPF(1.0f + EXP2F(pre)); \
    float av = fmaf(m1c, r_, m0c); \
    float iv = QB(av, 0); \
    float fv = QB(av, 1); \
    float gv = QB(av, 2); \
    float ov = QB(av, 3); \
    cs = fmaf(fv, cs, iv * gv); \
    float th_ = fmaf(2.0f, RCPF(1.0f + EXP2F(cs)), -1.0f); \
    h = ov * th_; }

    float* const xrow = &xg[w][row][0];

    for (int c = 0; c < 16; ++c) {
        const int t0 = c * 32;

        // ---- Phase A: bulk x-projection for this chunk (parallel) ----
#pragma unroll 2
        for (int tt = 0; tt < 32; tt += 4) {
            X4 v0 = xt[t0 + tt + 0];
            X4 v1 = xt[t0 + tt + 1];
            X4 v2 = xt[t0 + tt + 2];
            X4 v3 = xt[t0 + tt + 3];
            float4 d;
            d.x = DOTB(v0);
            d.y = DOTB(v1);
            d.z = DOTB(v2);
            d.w = DOTB(v3);
            *reinterpret_cast<float4*>(&xrow[tt]) = d;
        }

        // ---- Phase B: recurrence over the chunk (chain + 1 ds_read/4 steps) ----
        float4 xq = *reinterpret_cast<const float4*>(&xrow[0]);
#pragma unroll
        for (int tg = 0; tg < 8; ++tg) {
            float4 xn;
            if (tg < 7) xn = *reinterpret_cast<const float4*>(&xrow[(tg + 1) * 4]);
            STEP(xq.x);
            STEP(xq.y);
            STEP(xq.z);
            STEP(xq.w);
            if (tg < 7) xq = xn;
        }
    }

    // ---- MLP head (runs once; verified R2/R6/R7) ----
    float hA = h;
    float hB = SWZ(h, 4), hC = SWZ(h, 8), hD = SWZ(h, 12);

    float p0 = 0.f, p1 = 0.f, p2 = 0.f, p3 = 0.f, p4 = 0.f;
#pragma unroll
    for (int r = 0; r < 4; ++r) {
        const int u = i16 * 4 + r;            // hidden unit of layer 1, 4 per lane
        float acc = b1[u];
        acc = fmaf(hA, W1[(j ^ 0) * 64 + u], acc);
        acc = fmaf(hB, W1[(j ^ 1) * 64 + u], acc);
        acc = fmaf(hC, W1[(j ^ 2) * 64 + u], acc);
        acc = fmaf(hD, W1[(j ^ 3) * 64 + u], acc);
        acc = fmaxf(acc, 0.0f);
        p0 = fmaf(acc, W2[u * 5 + 0], p0);
        p1 = fmaf(acc, W2[u * 5 + 1], p1);
        p2 = fmaf(acc, W2[u * 5 + 2], p2);
        p3 = fmaf(acc, W2[u * 5 + 3], p3);
        p4 = fmaf(acc, W2[u * 5 + 4], p4);
    }
    // butterfly all-reduce across the 16-lane group
    p0 += SWZ(p0, 1); p1 += SWZ(p1, 1); p2 += SWZ(p2, 1); p3 += SWZ(p3, 1); p4 += SWZ(p4, 1);
    p0 += SWZ(p0, 2); p1 += SWZ(p1, 2); p2 += SWZ(p2, 2); p3 += SWZ(p3, 2); p4 += SWZ(p4, 2);
    p0 += SWZ(p0, 4); p1 += SWZ(p1, 4); p2 += SWZ(p2, 4); p3 += SWZ(p3, 4); p4 += SWZ(p4, 4);
    p0 += SWZ(p0, 8); p1 += SWZ(p1, 8); p2 += SWZ(p2, 8); p3 += SWZ(p3, 8); p4 += SWZ(p4, 8);

    p0 += b2[0]; p1 += b2[1]; p2 += b2[2]; p3 += b2[3]; p4 += b2[4];

    float mx = fmaxf(fmaxf(fmaxf(p0, p1), fmaxf(p2, p3)), p4);
    float e0 = EXP2F((p0 - mx) * LOG2E);
    float e1 = EXP2F((p1 - mx) * LOG2E);
    float e2 = EXP2F((p2 - mx) * LOG2E);
    float e3 = EXP2F((p3 - mx) * LOG2E);
    float e4 = EXP2F((p4 - mx) * LOG2E);
    float s = ((e0 + e1) + (e2 + e3)) + e4;
    float rs = RCPF(s);

    if (i16 == 0) {
        float* op = out + (size_t)seq * 5;
        op[0] = e0 * rs; op[1] = e1 * rs; op[2] = e2 * rs;
        op[3] = e3 * rs; op[4] = e4 * rs;
    }
}

extern "C" void kernel_launch(void* const* d_in, const int* in_sizes, int n_in,
                              void* d_out, int out_size, void* d_ws, size_t ws_size,
                              hipStream_t stream) {
    const float* x  = (const float*)d_in[0];
    const float* Wk = (const float*)d_in[1];
    const float* Wr = (const float*)d_in[2];
    const float* bg = (const float*)d_in[3];
    const float* W1 = (const float*)d_in[4];
    const float* b1 = (const float*)d_in[5];
    const float* W2 = (const float*)d_in[6];
    const float* b2 = (const float*)d_in[7];
    float* out = (float*)d_out;

    const int B = in_sizes[0] / (TLEN * 16);   // 4096
    dim3 block(256);
    dim3 grid(B / 16);                         // 16 seqs per block (4 per wave)
    lstm_mlp_kernel<<<grid, block, 0, stream>>>(x, Wk, Wr, bg, W1, b1, W2, b2, out, B);
}

// Round 9
// 112.370 us; speedup vs baseline: 1.0587x; 1.0587x over previous
//
#include <hip/hip_runtime.h>

#define TLEN 512
#define LOG2E 1.44269504088896340736f

#if __has_builtin(__builtin_amdgcn_exp2f)
#define EXP2F(x) __builtin_amdgcn_exp2f(x)
#else
#define EXP2F(x) __exp2f(x)
#endif
#if __has_builtin(__builtin_amdgcn_rcpf)
#define RCPF(x) __builtin_amdgcn_rcpf(x)
#else
#define RCPF(x) (1.0f / (x))
#endif

// ds_swizzle BitMode xor. 0x401F = lane^16 (guide's verified butterfly mask);
// operates within each 32-lane group -> seq A (lanes 0-31) and seq B (32-63)
// exchange independently. Used OFF the chain (4-step software pipeline).
#define SWZ(v, xm) __int_as_float(__builtin_amdgcn_ds_swizzle(__float_as_int(v), (((xm) << 10) | 0x1F)))
#define SWZ16(v)   __int_as_float(__builtin_amdgcn_ds_swizzle(__float_as_int(v), 0x401F))
// Generic DPP: row-of-16 confined ops (verified R1/R2/R6/R7/R8, absmax 0)
#define DPPF(v, ctrl) __int_as_float(__builtin_amdgcn_update_dpp(__float_as_int(v), __float_as_int(v), (ctrl), 0xF, 0xF, false))
#define QB(v, k) DPPF(v, 0x55 * (k))
#define XOR3(v)  DPPF(v, 0x1B)   // quad_perm [3,2,1,0]
#define XOR7(v)  DPPF(v, 0x141)  // ROW_HALF_MIRROR
#define XOR8(v)  DPPF(v, 0x128)  // ROW_ROR:8

struct XH { float4 a, b; };   // this lane's 8-feature half of one timestep (32 B)

// 32 lanes/seq => 131072 threads = 2048 waves = 2 waves/SIMD. Each half-group
// of 16 lanes computes an 8-feature partial x-dot; halves combine via lane^16
// swizzle, pipelined 4 steps ahead of the chain. STEP runs replicated in both
// halves (identical values). Second wave per SIMD fills chain/memory stalls.
__global__ __launch_bounds__(256)
__attribute__((amdgpu_waves_per_eu(2, 2)))
void lstm_mlp_kernel(
    const float* __restrict__ x,   // [B,512,16]
    const float* __restrict__ Wk,  // [16,16]
    const float* __restrict__ Wr,  // [4,16]
    const float* __restrict__ bg,  // [16]
    const float* __restrict__ W1,  // [4,64]
    const float* __restrict__ b1,  // [64]
    const float* __restrict__ W2,  // [64,5]
    const float* __restrict__ b2,  // [5]
    float* __restrict__ out,       // [B,5]
    int B)
{
    const int tid  = blockIdx.x * 256 + threadIdx.x;
    const int seq  = tid >> 5;         // 32 lanes per sequence
    const int half = (tid >> 4) & 1;   // feature half: 0 -> f0..7, 1 -> f8..15
    const int i16  = tid & 15;
    const int j    = i16 >> 2;         // hidden unit owned by this quad
    const int q    = i16 & 3;          // gate type: 0=i, 1=f, 2=g(tanh), 3=o
    const int gate = q * 4 + j;        // column in gates[16] (Keras i,f,g,o)

    // activation pre-scale folded into weights (verified R2/R6/R7/R8, absmax 0)
    const bool is_g = (q == 2);
    const float k1 = is_g ? (-2.0f * LOG2E) : (-LOG2E);
    const float m1c = is_g ? (-4.0f * LOG2E) : 1.0f;
    const float m0c = is_g ? (2.0f * LOG2E) : 0.0f;

    float wk[8];
#pragma unroll
    for (int f = 0; f < 8; ++f) wk[f] = k1 * Wk[(half * 8 + f) * 16 + gate];
    const float wr0 = k1 * Wr[(j ^ 0) * 16 + gate];
    const float wr1 = k1 * Wr[(j ^ 1) * 16 + gate];
    const float wr2 = k1 * Wr[(j ^ 2) * 16 + gate];
    const float wr3 = k1 * Wr[(j ^ 3) * 16 + gate];
    const float biasS = (half == 0) ? (k1 * bg[gate]) : 0.0f;  // bias counted once after halves sum

    // lane's 32-B slice of each timestep: x[seq][t][half*8 .. half*8+7]
    const float4* bp = reinterpret_cast<const float4*>(x + (size_t)seq * TLEN * 16 + half * 8);

    float cs = 0.0f, h = 0.0f;   // cs = -2*log2e * c

#define DOT4S(v, w0_, w1_, w2_, w3_, seed) \
    fmaf((v).x, (w0_), fmaf((v).y, (w1_), fmaf((v).z, (w2_), fmaf((v).w, (w3_), (seed)))))
#define DOT8(S) \
    (DOT4S((S).a, wk[0], wk[1], wk[2], wk[3], biasS) + \
     DOT4S((S).b, wk[4], wk[5], wk[6], wk[7], 0.0f))
#define LOADS(S, T) { S.a = bp[(size_t)(T) * 4]; S.b = bp[(size_t)(T) * 4 + 1]; }
// partial dot + cross-half combine (both halves end with the full xd)
#define MKXD(S, X) { float pd_ = DOT8(S); X = pd_ + SWZ16(pd_); }

#define STEP(XD) { \
    float h1_ = XOR7(XOR3(h));   /* h[j^1] */ \
    float h2_ = XOR8(h);         /* h[j^2] */ \
    float h3_ = XOR8(h1_);       /* h[j^3] */ \
    float preA = fmaf(h, wr0, fmaf(h1_, wr1, (XD))); \
    float preB = fmaf(h2_, wr2, h3_ * wr3); \
    float pre = preA + preB; \
    float r_ = RCPF(1.0f + EXP2F(pre)); \
    float av = fmaf(m1c, r_, m0c); \
    float iv = QB(av, 0); \
    float fv = QB(av, 1); \
    float gv = QB(av, 2); \
    float ov = QB(av, 3); \
    cs = fmaf(fv, cs, iv * gv); \
    float th_ = fmaf(2.0f, RCPF(1.0f + EXP2F(cs)), -1.0f); \
    h = ov * th_; }

// body at step t: consume xd[t] (X0, computed 4 steps ago), advance pipeline,
// build xd[t+4] from slot S (holds t+4), refill S with timestep TN = t+12.
#define BODY(S, TN) { \
    STEP(X0); X0 = X1; X1 = X2; X2 = X3; \
    MKXD(S, X3); \
    LOADS(S, TN); }

#define MIN511(a) ((a) > 511 ? 511 : (a))

    // 8-slot ring (64 VGPRs), timestep t lives in slot t&7
    XH S0, S1, S2, S3, S4, S5, S6, S7;
    LOADS(S0, 0); LOADS(S1, 1); LOADS(S2, 2); LOADS(S3, 3);
    LOADS(S4, 4); LOADS(S5, 5); LOADS(S6, 6); LOADS(S7, 7);

    // xd pipeline: X0..X3 = xd[0..3]
    float X0, X1, X2, X3;
    MKXD(S0, X0); MKXD(S1, X1); MKXD(S2, X2); MKXD(S3, X3);

    // main loop: steps t..t+7; body k uses slot (t+k+4)&7 = S4..S7,S0..S3.
    // Clamped refills (late iterations) write t=511 data into slots whose pd
    // would be for t>=512 -> never consumed, harmless.
#pragma clang loop unroll(disable)
    for (int t = 0; t < 504; t += 8) {
        const int tn = t + 12;
        BODY(S4, MIN511(tn));
        BODY(S5, MIN511(tn + 1));
        BODY(S6, MIN511(tn + 2));
        BODY(S7, MIN511(tn + 3));
        BODY(S0, MIN511(tn + 4));
        BODY(S1, MIN511(tn + 5));
        BODY(S2, MIN511(tn + 6));
        BODY(S3, MIN511(tn + 7));
    }
    // epilogue: steps 504..507 build the last pds (508..511 in slots S4..S7)
    { STEP(X0); X0 = X1; X1 = X2; X2 = X3; MKXD(S4, X3); }  // t=504, pd 508
    { STEP(X0); X0 = X1; X1 = X2; X2 = X3; MKXD(S5, X3); }  // 505 -> 509
    { STEP(X0); X0 = X1; X1 = X2; X2 = X3; MKXD(S6, X3); }  // 506 -> 510
    { STEP(X0); X0 = X1; X1 = X2; X2 = X3; MKXD(S7, X3); }  // 507 -> 511
    STEP(X0); STEP(X1); STEP(X2); STEP(X3);                 // 508..511

    // ---- MLP head (runs once; verified R2/R6/R7/R8). All four 16-lane
    // groups hold valid h; compute everywhere, write from lane (tid&31)==0.
    float hA = h;
    float hB = SWZ(h, 4), hC = SWZ(h, 8), hD = SWZ(h, 12);

    float p0 = 0.f, p1 = 0.f, p2 = 0.f, p3 = 0.f, p4 = 0.f;
#pragma unroll
    for (int r = 0; r < 4; ++r) {
        const int u = i16 * 4 + r;            // hidden unit of layer 1, 4 per lane
        float acc = b1[u];
        acc = fmaf(hA, W1[(j ^ 0) * 64 + u], acc);
        acc = fmaf(hB, W1[(j ^ 1) * 64 + u], acc);
        acc = fmaf(hC, W1[(j ^ 2) * 64 + u], acc);
        acc = fmaf(hD, W1[(j ^ 3) * 64 + u], acc);
        acc = fmaxf(acc, 0.0f);
        p0 = fmaf(acc, W2[u * 5 + 0], p0);
        p1 = fmaf(acc, W2[u * 5 + 1], p1);
        p2 = fmaf(acc, W2[u * 5 + 2], p2);
        p3 = fmaf(acc, W2[u * 5 + 3], p3);
        p4 = fmaf(acc, W2[u * 5 + 4], p4);
    }
    // butterfly all-reduce within each 16-lane group (masks < 16)
    p0 += SWZ(p0, 1); p1 += SWZ(p1, 1); p2 += SWZ(p2, 1); p3 += SWZ(p3, 1); p4 += SWZ(p4, 1);
    p0 += SWZ(p0, 2); p1 += SWZ(p1, 2); p2 += SWZ(p2, 2); p3 += SWZ(p3, 2); p4 += SWZ(p4, 2);
    p0 += SWZ(p0, 4); p1 += SWZ(p1, 4); p2 += SWZ(p2, 4); p3 += SWZ(p3, 4); p4 += SWZ(p4, 4);
    p0 += SWZ(p0, 8); p1 += SWZ(p1, 8); p2 += SWZ(p2, 8); p3 += SWZ(p3, 8); p4 += SWZ(p4, 8);

    p0 += b2[0]; p1 += b2[1]; p2 += b2[2]; p3 += b2[3]; p4 += b2[4];

    float mx = fmaxf(fmaxf(fmaxf(p0, p1), fmaxf(p2, p3)), p4);
    float e0 = EXP2F((p0 - mx) * LOG2E);
    float e1 = EXP2F((p1 - mx) * LOG2E);
    float e2 = EXP2F((p2 - mx) * LOG2E);
    float e3 = EXP2F((p3 - mx) * LOG2E);
    float e4 = EXP2F((p4 - mx) * LOG2E);
    float s = ((e0 + e1) + (e2 + e3)) + e4;
    float rs = RCPF(s);

    if ((tid & 31) == 0) {
        float* op = out + (size_t)seq * 5;
        op[0] = e0 * rs; op[1] = e1 * rs; op[2] = e2 * rs;
        op[3] = e3 * rs; op[4] = e4 * rs;
    }
}

extern "C" void kernel_launch(void* const* d_in, const int* in_sizes, int n_in,
                              void* d_out, int out_size, void* d_ws, size_t ws_size,
                              hipStream_t stream) {
    const float* x  = (const float*)d_in[0];
    const float* Wk = (const float*)d_in[1];
    const float* Wr = (const float*)d_in[2];
    const float* bg = (const float*)d_in[3];
    const float* W1 = (const float*)d_in[4];
    const float* b1 = (const float*)d_in[5];
    const float* W2 = (const float*)d_in[6];
    const float* b2 = (const float*)d_in[7];
    float* out = (float*)d_out;

    const int B = in_sizes[0] / (TLEN * 16);   // 4096
    const int threads = B * 32;                // 32 lanes per sequence
    dim3 block(256);
    dim3 grid((threads + 255) / 256);
    lstm_mlp_kernel<<<grid, block, 0, stream>>>(x, Wk, Wr, bg, W1, b1, W2, b2, out, B);
}

// Round 10
// 82.161 us; speedup vs baseline: 1.4479x; 1.3677x over previous
//
#include <hip/hip_runtime.h>

#define TLEN 512
#define LOG2E 1.44269504088896340736f

#if __has_builtin(__builtin_amdgcn_exp2f)
#define EXP2F(x) __builtin_amdgcn_exp2f(x)
#else
#define EXP2F(x) __exp2f(x)
#endif
#if __has_builtin(__builtin_amdgcn_rcpf)
#define RCPF(x) __builtin_amdgcn_rcpf(x)
#else
#define RCPF(x) (1.0f / (x))
#endif

// ds_swizzle BitMode xor (epilogue MLP head only, off the hot loop)
#define SWZ(v, xm) __int_as_float(__builtin_amdgcn_ds_swizzle(__float_as_int(v), (((xm) << 10) | 0x1F)))
// Generic DPP: dst = src[permuted lane], all lanes valid
#define DPPF(v, ctrl) __int_as_float(__builtin_amdgcn_update_dpp(__float_as_int(v), __float_as_int(v), (ctrl), 0xF, 0xF, false))
// quad_perm broadcast of quad-lane k
#define QB(v, k) DPPF(v, 0x55 * (k))
// Direction-free lane exchanges within a row of 16 (verified R1-R9, absmax 0):
#define XOR3(v)  DPPF(v, 0x1B)   // quad_perm [3,2,1,0]
#define XOR7(v)  DPPF(v, 0x141)  // ROW_HALF_MIRROR
#define XOR8(v)  DPPF(v, 0x128)  // ROW_ROR:8

// counted vmcnt wait + full scheduling fence (rule #18). The fence also makes
// the R6-proven vmcnt arithmetic exact: nothing (including epilogue weight
// loads) can migrate across iteration boundaries.
#define WAITVM(N) { \
    asm volatile("s_waitcnt vmcnt(" #N ")" ::: "memory"); \
    __builtin_amdgcn_sched_barrier(0); }

typedef const __attribute__((address_space(1))) unsigned int gu32;
typedef __attribute__((address_space(3))) unsigned int lu32;

// R10 = R6's global_load_lds DMA ring (proven correct: fire-and-forget, no
// destination register for RA to corrupt) + waves_per_eu(1,1) (full VGPR
// budget, R7-proven) + group-ahead refill: the chain consumes only register
// xd values; the next group's 16 LDS reads + 64 dot-FMAs are independent
// work the scheduler interleaves under ~400cy of chain latency.
__global__ __launch_bounds__(256)
__attribute__((amdgpu_waves_per_eu(1, 1)))
void lstm_mlp_kernel(
    const float* __restrict__ x,   // [B,512,16]
    const float* __restrict__ Wk,  // [16,16]
    const float* __restrict__ Wr,  // [4,16]
    const float* __restrict__ bg,  // [16]
    const float* __restrict__ W1,  // [4,64]
    const float* __restrict__ b1,  // [64]
    const float* __restrict__ W2,  // [64,5]
    const float* __restrict__ b2,  // [5]
    float* __restrict__ out,       // [B,5]
    int B)
{
    // per-wave private LDS ring: [wave][slot][dt*16 + chunk*4 + seq] float4
    // slot = one group of 4 timesteps (1KB). No barriers anywhere.
    __shared__ float4 lds[4][4][64];

    const int tidx = threadIdx.x;
    const int w   = tidx >> 6;         // wave in block
    const int L   = tidx & 63;         // lane
    const int sl  = (tidx >> 4) & 3;   // seq-local within wave
    const int i16 = tidx & 15;
    const int j   = i16 >> 2;          // hidden unit owned by this quad
    const int q   = i16 & 3;           // gate type: 0=i, 1=f, 2=g(tanh), 3=o
    const int gate = q * 4 + j;        // column in gates[16] (Keras i,f,g,o)
    const int seq = blockIdx.x * 16 + (tidx >> 4);

    // activation pre-scale folded into weights (verified R2/R6/R7/R8/R9)
    const bool is_g = (q == 2);
    const float k1 = is_g ? (-2.0f * LOG2E) : (-LOG2E);
    const float m1c = is_g ? (-4.0f * LOG2E) : 1.0f;
    const float m0c = is_g ? (2.0f * LOG2E) : 0.0f;

    float wk[16];
#pragma unroll
    for (int f = 0; f < 16; ++f) wk[f] = k1 * Wk[f * 16 + gate];
    const float wr0 = k1 * Wr[(j ^ 0) * 16 + gate];
    const float wr1 = k1 * Wr[(j ^ 1) * 16 + gate];
    const float wr2 = k1 * Wr[(j ^ 2) * 16 + gate];
    const float wr3 = k1 * Wr[(j ^ 3) * 16 + gate];
    const float biasS = k1 * bg[gate];

    // DMA lane mapping (R6-proven): lane L fetches 16B of (seq L&3,
    // timestep t0 + (L>>4), floats ((L>>2)&3)*4..+3); linear LDS dest
    // base + L*16 gives layout [dt][chunk][seq] float4.
    const int dseq = L & 3;
    const int dtl  = L >> 4;
    const int chnk = (L >> 2) & 3;
    const float* xb = x + ((size_t)(blockIdx.x * 16 + w * 4 + dseq) * TLEN + dtl) * 16 + chnk * 4;

#define DMA(SLOT, T0) \
    __builtin_amdgcn_global_load_lds((gu32*)(const void*)(xb + (size_t)(T0) * 16), \
                                     (lu32*)(void*)(&lds[w][SLOT][0]), 16, 0, 0)

    float cs = 0.0f, h = 0.0f;   // cs = -2*log2e * c

#define DOT4S(v, w0_, w1_, w2_, w3_, seed) \
    fmaf((v).x, (w0_), fmaf((v).y, (w1_), fmaf((v).z, (w2_), fmaf((v).w, (w3_), (seed)))))
#define DOTQ(Ra, Rb, Rc, Rd) \
    ((DOT4S((Ra), wk[0], wk[1], wk[2], wk[3], biasS) + \
      DOT4S((Rb), wk[4], wk[5], wk[6], wk[7], 0.0f)) + \
     (DOT4S((Rc), wk[8], wk[9], wk[10], wk[11], 0.0f) + \
      DOT4S((Rd), wk[12], wk[13], wk[14], wk[15], 0.0f)))

// read one group (4 timesteps) from an LDS slot and produce its 4 dots.
// 16 ds_read_b128 + 64 FMA, all independent of the recurrence chain.
#define REFILL(SLOT, XDN) { \
    const float4* lg_ = &lds[w][SLOT][0]; \
    float4 A0=lg_[sl+ 0], A1=lg_[sl+ 4], A2=lg_[sl+ 8], A3=lg_[sl+12]; \
    float4 B0=lg_[sl+16], B1=lg_[sl+20], B2=lg_[sl+24], B3=lg_[sl+28]; \
    float4 C0=lg_[sl+32], C1=lg_[sl+36], C2=lg_[sl+40], C3=lg_[sl+44]; \
    float4 D0=lg_[sl+48], D1=lg_[sl+52], D2=lg_[sl+56], D3=lg_[sl+60]; \
    (XDN).x = DOTQ(A0, A1, A2, A3); \
    (XDN).y = DOTQ(B0, B1, B2, B3); \
    (XDN).z = DOTQ(C0, C1, C2, C3); \
    (XDN).w = DOTQ(D0, D1, D2, D3); }

// tree-shaped preactivation sum, then the LSTM cell update (verified R8/R9)
#define STEP(XD) { \
    float h1_ = XOR7(XOR3(h));   /* h[j^1] */ \
    float h2_ = XOR8(h);         /* h[j^2] */ \
    float h3_ = XOR8(h1_);       /* h[j^3] */ \
    float preA = fmaf(h, wr0, fmaf(h1_, wr1, (XD))); \
    float preB = fmaf(h2_, wr2, h3_ * wr3); \
    float pre = preA + preB; \
    float r_ = RCPF(1.0f + EXP2F(pre)); \
    float av = fmaf(m1c, r_, m0c); \
    float iv = QB(av, 0); \
    float fv = QB(av, 1); \
    float gv = QB(av, 2); \
    float ov = QB(av, 3); \
    cs = fmaf(fv, cs, iv * gv); \
    float th_ = fmaf(2.0f, RCPF(1.0f + EXP2F(cs)), -1.0f); \
    h = ov * th_; }

    // prologue: clean vmcnt baseline, fill 4 slots (groups 0..3)
    WAITVM(0);
    DMA(0, 0);
    DMA(1, 4);
    DMA(2, 8);
    DMA(3, 12);
    WAITVM(3);                 // group 0 resident
    float4 xd;
    REFILL(0, xd);             // dots for group 0 (steps 0..3)

    // main loop: iter g chains steps 4g..4g+3 from xd, refills xdn from
    // group g+1 (resident via vmcnt(2), R6-proven count), then DMAs group
    // g+4 into slot g&3 (clamped tail rewrites are never consumed).
#pragma clang loop unroll(disable)
    for (int g = 0; g < 127; ++g) {
        WAITVM(2);
        float4 xdn;
        REFILL((g + 1) & 3, xdn);
        STEP(xd.x);
        STEP(xd.y);
        STEP(xd.z);
        STEP(xd.w);
        int t0 = (g + 4) << 2;
        t0 = t0 > (TLEN - 4) ? (TLEN - 4) : t0;
        DMA(g & 3, t0);
        xd = xdn;
    }
    // final group 127: pure chain
    STEP(xd.x);
    STEP(xd.y);
    STEP(xd.z);
    STEP(xd.w);
    WAITVM(0);   // drain trailing DMAs before epilogue / endpgm

    // ---- MLP head (runs once; verified R2/R6-R9) ----
    float hA = h;
    float hB = SWZ(h, 4), hC = SWZ(h, 8), hD = SWZ(h, 12);

    float p0 = 0.f, p1 = 0.f, p2 = 0.f, p3 = 0.f, p4 = 0.f;
#pragma unroll
    for (int r = 0; r < 4; ++r) {
        const int u = i16 * 4 + r;            // hidden unit of layer 1, 4 per lane
        float acc = b1[u];
        acc = fmaf(hA, W1[(j ^ 0) * 64 + u], acc);
        acc = fmaf(hB, W1[(j ^ 1) * 64 + u], acc);
        acc = fmaf(hC, W1[(j ^ 2) * 64 + u], acc);
        acc = fmaf(hD, W1[(j ^ 3) * 64 + u], acc);
        acc = fmaxf(acc, 0.0f);
        p0 = fmaf(acc, W2[u * 5 + 0], p0);
        p1 = fmaf(acc, W2[u * 5 + 1], p1);
        p2 = fmaf(acc, W2[u * 5 + 2], p2);
        p3 = fmaf(acc, W2[u * 5 + 3], p3);
        p4 = fmaf(acc, W2[u * 5 + 4], p4);
    }
    // butterfly all-reduce across the 16-lane group
    p0 += SWZ(p0, 1); p1 += SWZ(p1, 1); p2 += SWZ(p2, 1); p3 += SWZ(p3, 1); p4 += SWZ(p4, 1);
    p0 += SWZ(p0, 2); p1 += SWZ(p1, 2); p2 += SWZ(p2, 2); p3 += SWZ(p3, 2); p4 += SWZ(p4, 2);
    p0 += SWZ(p0, 4); p1 += SWZ(p1, 4); p2 += SWZ(p2, 4); p3 += SWZ(p3, 4); p4 += SWZ(p4, 4);
    p0 += SWZ(p0, 8); p1 += SWZ(p1, 8); p2 += SWZ(p2, 8); p3 += SWZ(p3, 8); p4 += SWZ(p4, 8);

    p0 += b2[0]; p1 += b2[1]; p2 += b2[2]; p3 += b2[3]; p4 += b2[4];

    float mx = fmaxf(fmaxf(fmaxf(p0, p1), fmaxf(p2, p3)), p4);
    float e0 = EXP2F((p0 - mx) * LOG2E);
    float e1 = EXP2F((p1 - mx) * LOG2E);
    float e2 = EXP2F((p2 - mx) * LOG2E);
    float e3 = EXP2F((p3 - mx) * LOG2E);
    float e4 = EXP2F((p4 - mx) * LOG2E);
    float s = ((e0 + e1) + (e2 + e3)) + e4;
    float rs = RCPF(s);

    if (i16 == 0) {
        float* op = out + (size_t)seq * 5;
        op[0] = e0 * rs; op[1] = e1 * rs; op[2] = e2 * rs;
        op[3] = e3 * rs; op[4] = e4 * rs;
    }
}

extern "C" void kernel_launch(void* const* d_in, const int* in_sizes, int n_in,
                              void* d_out, int out_size, void* d_ws, size_t ws_size,
                              hipStream_t stream) {
    const float* x  = (const float*)d_in[0];
    const float* Wk = (const float*)d_in[1];
    const float* Wr = (const float*)d_in[2];
    const float* bg = (const float*)d_in[3];
    const float* W1 = (const float*)d_in[4];
    const float* b1 = (const float*)d_in[5];
    const float* W2 = (const float*)d_in[6];
    const float* b2 = (const float*)d_in[7];
    float* out = (float*)d_out;

    const int B = in_sizes[0] / (TLEN * 16);   // 4096
    dim3 block(256);
    dim3 grid(B / 16);                         // 16 seqs per block (4 per wave)
    lstm_mlp_kernel<<<grid, block, 0, stream>>>(x, Wk, Wr, bg, W1, b1, W2, b2, out, B);
}